// Round 2
// baseline (600.624 us; speedup 1.0000x reference)
//
#include <hip/hip_runtime.h>
#include <hip/hip_bf16.h>

typedef unsigned short u16;
typedef __attribute__((ext_vector_type(8))) short short8;
typedef __attribute__((ext_vector_type(4))) float floatx4;

#define R_PDS 0.18033688f     // r_softplus_0 / sqrt(64)
#define LOG2E 1.4426950408889634f

__device__ __forceinline__ float bf2f(u16 u) {
    union { float f; unsigned int i; } c; c.i = ((unsigned int)u) << 16; return c.f;
}
__device__ __forceinline__ u16 f2b(float f) {
    union { float f; unsigned int i; } c; c.f = f;
    unsigned int r = c.i + 0x7fffu + ((c.i >> 16) & 1u);
    return (u16)(r >> 16);
}
// packed fp32x2 -> bf16x2 (RNE), lo=a hi=b
__device__ __forceinline__ unsigned int pk2(float a, float b) {
    __hip_bfloat162 h = __float22bfloat162_rn(float2{a, b});
    unsigned int u; __builtin_memcpy(&u, &h, 4); return u;
}

// async global->LDS, 16B per lane. LDS dest is wave-uniform base + lane*16.
__device__ __forceinline__ void async16(const u16* g, u16* l) {
    __builtin_amdgcn_global_load_lds(
        (const __attribute__((address_space(1))) unsigned int*)g,
        (__attribute__((address_space(3))) unsigned int*)l, 16, 0, 0);
}

// ---------------- all weight fp32->bf16 converts in ONE kernel (+flag zero) ------------
__global__ __launch_bounds__(256) void f2b_all_k(const float* __restrict__ Wq, const float* __restrict__ Wk,
                                                 const float* __restrict__ Wv, const float* __restrict__ Wp,
                                                 const float* __restrict__ W1, const float* __restrict__ W2,
                                                 u16* __restrict__ Wqkvb, u16* __restrict__ Wpb,
                                                 u16* __restrict__ W1b,  u16* __restrict__ W2b,
                                                 int* flag) {
    int bid = blockIdx.x;
    if (bid == 0 && threadIdx.x == 0) *flag = 0;
    const float* src; u16* dst; int off;
    if      (bid < 1024) { src = Wq; dst = Wqkvb;                off = bid; }
    else if (bid < 2048) { src = Wk; dst = Wqkvb + 1024 * 1024;  off = bid - 1024; }
    else if (bid < 3072) { src = Wv; dst = Wqkvb + 2048 * 1024;  off = bid - 2048; }
    else if (bid < 4096) { src = Wp; dst = Wpb;                  off = bid - 3072; }
    else if (bid < 8192) { src = W1; dst = W1b;                  off = bid - 4096; }
    else                 { src = W2; dst = W2b;                  off = bid - 8192; }
    int i = off * 256 + threadIdx.x;
    float4 v = ((const float4*)src)[i];
    uint2 w; w.x = pk2(v.x, v.y); w.y = pk2(v.z, v.w);
    ((uint2*)dst)[i] = w;
}

__global__ __launch_bounds__(256) void mask_any_k(const float* __restrict__ mask, int* flag) {
    int i = blockIdx.x * 256 + threadIdx.x;
    uint4 u = ((const uint4*)mask)[i];
    unsigned int v = (u.x | u.y | u.z | u.w) & 0x7fffffffu;
    if (v) atomicOr(flag, 1);
}

// ---------------- RMSNorm (row = 1024 fp32) -> bf16 ----------------
__global__ __launch_bounds__(256) void rmsnorm_k(const float* __restrict__ in,
                                                 const float* __restrict__ gscale,
                                                 u16* __restrict__ out) {
    int row = blockIdx.x;
    int t = threadIdx.x, lane = t & 63, wave = t >> 6;
    const float* x = in + (size_t)row * 1024;
    float4 v = *(const float4*)(x + t * 4);
    float ss = v.x*v.x + v.y*v.y + v.z*v.z + v.w*v.w;
    for (int o = 1; o < 64; o <<= 1) ss += __shfl_xor(ss, o, 64);
    __shared__ float red[4];
    if (lane == 0) red[wave] = ss;
    __syncthreads();
    float tot = red[0] + red[1] + red[2] + red[3];
    float inv = rsqrtf(tot * (1.0f / 1024.0f) + 1e-6f);
    float4 s = *(const float4*)(gscale + t * 4);
    uint2 w;
    w.x = pk2(v.x * inv * s.x, v.y * inv * s.y);
    w.y = pk2(v.z * inv * s.z, v.w * inv * s.w);
    *(uint2*)(out + (size_t)row * 1024 + t * 4) = w;
}

// ---------------- LayerNorm (row = 1024 bf16 in, eff scale = 1+s) -> bf16 ----------------
__global__ __launch_bounds__(256) void layernorm_k(const u16* __restrict__ in,
                                                   const float* __restrict__ gs,
                                                   const float* __restrict__ gb,
                                                   u16* __restrict__ out) {
    int row = blockIdx.x;
    int t = threadIdx.x, lane = t & 63, wave = t >> 6;
    const u16* x = in + (size_t)row * 1024;
    uint2 u = *(const uint2*)(x + t * 4);
    float v0 = bf2f((u16)(u.x & 0xffff)), v1 = bf2f((u16)(u.x >> 16));
    float v2 = bf2f((u16)(u.y & 0xffff)), v3 = bf2f((u16)(u.y >> 16));
    float s1 = v0 + v1 + v2 + v3;
    float s2 = v0*v0 + v1*v1 + v2*v2 + v3*v3;
    for (int o = 1; o < 64; o <<= 1) { s1 += __shfl_xor(s1, o, 64); s2 += __shfl_xor(s2, o, 64); }
    __shared__ float r1[4], r2[4];
    if (lane == 0) { r1[wave] = s1; r2[wave] = s2; }
    __syncthreads();
    float mean = (r1[0] + r1[1] + r1[2] + r1[3]) * (1.0f / 1024.0f);
    float var  = (r2[0] + r2[1] + r2[2] + r2[3]) * (1.0f / 1024.0f) - mean * mean;
    var = fmaxf(var, 0.0f);
    float inv = rsqrtf(var + 1e-6f);
    float4 sc = *(const float4*)(gs + t * 4);
    float4 bb = *(const float4*)(gb + t * 4);
    uint2 w;
    w.x = pk2((v0 - mean) * inv * (1.0f + sc.x) + bb.x,
              (v1 - mean) * inv * (1.0f + sc.y) + bb.y);
    w.y = pk2((v2 - mean) * inv * (1.0f + sc.z) + bb.z,
              (v3 - mean) * inv * (1.0f + sc.w) + bb.w);
    *(uint2*)(out + (size_t)row * 1024 + t * 4) = w;
}

// ================= 8-phase 256x256 GEMM core (T1+T2+T3+T4+T5) =================
// BM=BN=256, BK=64, 512 thr = 8 waves (2M x 4N); per-wave C = 128x64 (8x4 frags).
// LDS 128 KiB: 2 bufs x {A0,A1,B0,B1} half-tiles (128 rows x 64 k bf16 = 16 KB).
// Staged linearly by global_load_lds(16B) with PRE-SWIZZLED source column
// (in-row byte ^= (row&7)<<4); ds_read applies same XOR -> ~conflict-free b128
// (rule 21: linear dest + inverse-swz source + swz read). Phase q of group g:
//   [4 A ds_reads (+8 B reads at q0) | stage 1 half-tile | s_barrier |
//    lgkmcnt(0) | setprio(1) 16 MFMA setprio(0) | (q3: vmcnt(4)) | s_barrier]
// Staging: q0/q1 -> A halves of T_{g+1} (other buf: its A dead since prev group
// close); q2/q3 -> B halves of T_{g+2} (cur buf: B dead after q0 close).
// vmcnt(4) at q3 leaves the 2 next-B half-tiles in flight across the barrier
// (never drains to 0 in steady state = T4 counted-vmcnt).
__device__ __forceinline__ void gemm8_core(const u16* __restrict__ A, const u16* __restrict__ B,
                                           int K, int NG, int m0, int n0,
                                           u16* lds, floatx4 (&acc)[8][4]) {
    const int t = threadIdx.x, wave = t >> 6, lane = t & 63;
    const int quad = lane >> 4, ln = lane & 15;
    const int wave_m = wave >> 2, wave_n = wave & 3;

    // ---- staging geometry (per-thread, constant over groups) ----
    const int rowS = t >> 3;                                   // 0..63
    const int srcb = ((t & 7) * 16) ^ (((t >> 3) & 7) << 4);   // swizzled in-row byte
    const u16* Ab = A + (size_t)(m0 + rowS) * K + (srcb >> 1);
    const u16* Bb = B + (size_t)(n0 + rowS) * K + (srcb >> 1);
    const size_t rstep = (size_t)64 * K;                       // chunk-2 rows
    const size_t hstep = (size_t)128 * K;                      // half-1 rows
    const int ldw = wave * 512;                                // u16 wave slice in half

    #define STAGE_A8(buf, h, kt) do { \
        u16* _l = lds + (buf) * 32768 + (h) * 8192 + ldw; \
        const u16* _g = Ab + (size_t)(h) * hstep + (kt); \
        async16(_g, _l); async16(_g + rstep, _l + 4096); } while (0)
    #define STAGE_B8(buf, h, kt) do { \
        u16* _l = lds + (buf) * 32768 + 16384 + (h) * 8192 + ldw; \
        const u16* _g = Bb + (size_t)(h) * hstep + (kt); \
        async16(_g, _l); async16(_g + rstep, _l + 4096); } while (0)

    // fragment read from a half-tile base (u16*), local row lr, k-slice ks
    #define RD8(base, lr, ks) \
        (*(const short8*)((base) + (lr) * 64 + ((((ks) * 64 + quad * 16) ^ (((lr) & 7) << 4)) >> 1)))

    // ---- prologue: T0 fully + B halves of T1; drain T0, keep T1.B in flight ----
    STAGE_B8(0, 0, 0); STAGE_B8(0, 1, 0);
    STAGE_A8(0, 0, 0); STAGE_A8(0, 1, 0);
    if (NG > 1) {
        STAGE_B8(1, 0, 64); STAGE_B8(1, 1, 64);
        asm volatile("s_waitcnt vmcnt(4)" ::: "memory");
    } else {
        asm volatile("s_waitcnt vmcnt(0)" ::: "memory");
    }
    __builtin_amdgcn_s_barrier();

    for (int g = 0; g < NG; ++g) {
        const int cur = g & 1;
        const u16* aH = lds + cur * 32768 + wave_m * 8192;
        const u16* bH = lds + cur * 32768 + 16384 + (wave_n >> 1) * 8192;
        const int lrB = (wave_n & 1) * 64;
        short8 bf[4][2];
        #pragma unroll
        for (int q = 0; q < 4; ++q) {
            short8 af[2][2];
            #pragma unroll
            for (int mt = 0; mt < 2; ++mt)
                #pragma unroll
                for (int ks = 0; ks < 2; ++ks)
                    af[mt][ks] = RD8(aH, q * 32 + mt * 16 + ln, ks);
            if (q == 0) {
                #pragma unroll
                for (int nt = 0; nt < 4; ++nt)
                    #pragma unroll
                    for (int ks = 0; ks < 2; ++ks)
                        bf[nt][ks] = RD8(bH, lrB + nt * 16 + ln, ks);
            }
            if (q == 0 && g + 1 < NG) STAGE_A8(cur ^ 1, 0, (g + 1) * 64);
            if (q == 1 && g + 1 < NG) STAGE_A8(cur ^ 1, 1, (g + 1) * 64);
            if (q == 2 && g + 2 < NG) STAGE_B8(cur, 0, (g + 2) * 64);
            if (q == 3 && g + 2 < NG) STAGE_B8(cur, 1, (g + 2) * 64);
            __builtin_amdgcn_s_barrier();
            asm volatile("s_waitcnt lgkmcnt(0)" ::: "memory");
            __builtin_amdgcn_s_setprio(1);
            #pragma unroll
            for (int ks = 0; ks < 2; ++ks)
                #pragma unroll
                for (int mt = 0; mt < 2; ++mt)
                    #pragma unroll
                    for (int nt = 0; nt < 4; ++nt)
                        acc[q * 2 + mt][nt] = __builtin_amdgcn_mfma_f32_16x16x32_bf16(
                            af[mt][ks], bf[nt][ks], acc[q * 2 + mt][nt], 0, 0, 0);
            __builtin_amdgcn_s_setprio(0);
            __builtin_amdgcn_sched_barrier(0);
            if (q == 3 && g + 1 < NG) {
                if (g + 2 < NG) asm volatile("s_waitcnt vmcnt(4)" ::: "memory");
                else            asm volatile("s_waitcnt vmcnt(0)" ::: "memory");
            }
            __builtin_amdgcn_s_barrier();
        }
    }
    #undef STAGE_A8
    #undef STAGE_B8
    #undef RD8
}

// XCD-aware bijective swizzle of the linear block id (nwg % 8 == 0 at all call sites)
__device__ __forceinline__ void xcd_swizzle(int& bx, int& by) {
    int gx = gridDim.x, nwg = gx * gridDim.y;
    int lin = blockIdx.y * gx + blockIdx.x;
    int swz = (lin & 7) * (nwg >> 3) + (lin >> 3);
    bx = swz % gx; by = swz / gx;
}

// ---------------- 8-phase GEMM: C[M,N] = A[M,K] * B[N,K]^T + bias (+epilogue) ----------
template <int EPI, bool OUTF32, bool RESF32>
__global__ __launch_bounds__(512, 2) void gemm8_bt_k(const u16* __restrict__ A,
                                                     const u16* __restrict__ B,
                                                     const float* __restrict__ bias,
                                                     const void* __restrict__ res,
                                                     void* __restrict__ Cv,
                                                     int M, int N, int K) {
    __shared__ __align__(16) u16 lds[65536];   // 128 KiB
    int bx, by; xcd_swizzle(bx, by);
    const int m0 = by * 256, n0 = bx * 256;
    const int t = threadIdx.x, wave = t >> 6, lane = t & 63;
    const int quad = lane >> 4, ln = lane & 15;
    const int wm = (wave >> 2) * 128, wn = (wave & 3) * 64;

    floatx4 acc[8][4];
    #pragma unroll
    for (int mf = 0; mf < 8; mf++)
        #pragma unroll
        for (int nf = 0; nf < 4; nf++) acc[mf][nf] = (floatx4)0.0f;

    gemm8_core(A, B, K, K >> 6, m0, n0, lds, acc);

    #pragma unroll
    for (int nf = 0; nf < 4; nf++) {
        int col = n0 + wn + nf * 16 + ln;
        float bv = bias[col];
        #pragma unroll
        for (int mf = 0; mf < 8; mf++) {
            int row = m0 + wm + mf * 16 + quad * 4;
            #pragma unroll
            for (int r = 0; r < 4; r++) {
                float v = acc[mf][nf][r] + bv;
                if (EPI == 1) v = fmaxf(v, 0.0f);
                if (EPI == 2) {
                    if (RESF32) v += ((const float*)res)[(size_t)(row + r) * N + col];
                    else        v += bf2f(((const u16*)res)[(size_t)(row + r) * N + col]);
                }
                if (OUTF32) ((float*)Cv)[(size_t)(row + r) * N + col] = v;
                else        ((u16*)Cv)[(size_t)(row + r) * N + col] = f2b(v);
            }
        }
    }
}

// ---------------- 8-phase fused QKV GEMM: q cols scaled by softplus(pds)*LOG2E --------
__global__ __launch_bounds__(512, 2) void gemm8_qkv_k(const u16* __restrict__ A,
                                                      const u16* __restrict__ B,
                                                      const float* __restrict__ bq,
                                                      const float* __restrict__ bk,
                                                      const float* __restrict__ bv,
                                                      const float* __restrict__ pds,
                                                      u16* __restrict__ C) {
    const int K = 1024, N = 3072;
    __shared__ __align__(16) u16 lds[65536];
    int bx, by; xcd_swizzle(bx, by);
    const int m0 = by * 256, n0 = bx * 256;
    const int t = threadIdx.x, wave = t >> 6, lane = t & 63;
    const int quad = lane >> 4, ln = lane & 15;
    const int wm = (wave >> 2) * 128, wn = (wave & 3) * 64;

    floatx4 acc[8][4];
    #pragma unroll
    for (int mf = 0; mf < 8; mf++)
        #pragma unroll
        for (int nf = 0; nf < 4; nf++) acc[mf][nf] = (floatx4)0.0f;

    gemm8_core(A, B, K, K >> 6, m0, n0, lds, acc);

    #pragma unroll
    for (int nf = 0; nf < 4; nf++) {
        int col = n0 + wn + nf * 16 + ln;
        float bv_, sc = 1.0f;
        if (col < 1024) {
            bv_ = bq[col];
            float xp = pds[col & 63];
            float sp = (xp > 20.0f) ? xp : log1pf(__expf(xp));
            sc = R_PDS * sp * LOG2E;            // fold log2(e): attn uses exp2
        } else if (col < 2048) bv_ = bk[col - 1024];
        else                   bv_ = bv[col - 2048];
        #pragma unroll
        for (int mf = 0; mf < 8; mf++) {
            int row = m0 + wm + mf * 16 + quad * 4;
            #pragma unroll
            for (int r = 0; r < 4; r++)
                C[(size_t)(row + r) * N + col] = f2b((acc[mf][nf][r] + bv_) * sc);
        }
    }
}

// ---------------- V transpose: qkv v-part -> vT[bh][d][s] ----------------
__global__ __launch_bounds__(256) void transpose_v_k(const u16* __restrict__ qkv, u16* __restrict__ vT) {
    __shared__ u16 tile[64][65];
    int st = blockIdx.x, bh = blockIdx.y;
    int b = bh >> 4, h = bh & 15;
    const u16* vb = qkv + (size_t)(b * 2048 + st * 64) * 3072 + 2048 + h * 64;
    int t = threadIdx.x;
    for (int i = t; i < 4096; i += 256) {
        int s = i >> 6, d = i & 63;
        tile[s][d] = vb[(size_t)s * 3072 + d];
    }
    __syncthreads();
    u16* ob = vT + (size_t)bh * 131072 + st * 64;
    for (int i = t; i < 4096; i += 256) {
        int d = i >> 6, s = i & 63;
        ob[(size_t)d * 2048 + s] = tile[s][d];
    }
}

// ---------------- flash attention: 1 block = (bh, 128 q rows), BKV=64 ------------------
__global__ __launch_bounds__(256) void attn_k(const u16* __restrict__ qkv,
                                              const u16* __restrict__ vT,
                                              const float* __restrict__ mask,
                                              const int* __restrict__ flag,
                                              u16* __restrict__ o) {
    __shared__ __align__(16) u16 QPs[128][72];  // Q during setup, then P (rows wave-local)
    __shared__ __align__(16) u16 Ks[64][72];
    __shared__ __align__(16) u16 Vs[64][72];    // rows = d, cols = kv

    const int t = threadIdx.x, wave = t >> 6, lane = t & 63;
    const int quad = lane >> 4, ln = lane & 15;
    const int qt = blockIdx.x, bh = blockIdx.y;
    const int b = bh >> 4, h = bh & 15;
    const int q0 = qt * 128;
    const int wm = wave * 32;

    // stage Q tile (128 rows x 64 d; pre-scaled by softplus*log2e in QKV epilogue)
    const u16* qb = qkv + (size_t)(b * 2048 + q0) * 3072 + h * 64;
    for (int c = t; c < 1024; c += 256) {
        int row = c >> 3, seg = c & 7;
        *(uint4*)&QPs[row][seg * 8] = *(const uint4*)(qb + (size_t)row * 3072 + seg * 8);
    }
    __syncthreads();

    // hoist Q fragments (rows wm..wm+31: wave-local, same rows later P writes reuse)
    short8 qf[2][2];
    for (int mt = 0; mt < 2; mt++)
        for (int ks = 0; ks < 2; ks++)
            qf[mt][ks] = *(const short8*)&QPs[wm + mt * 16 + ln][ks * 32 + quad * 8];

    short8 ones_f;
    for (int i = 0; i < 8; i++) ones_f[i] = (short)0x3F80;   // bf16 1.0

    floatx4 acc_o[2][4], acc_l[2];
    for (int mt = 0; mt < 2; mt++) {
        acc_l[mt] = (floatx4)0.0f;
        for (int dt = 0; dt < 4; dt++) acc_o[mt][dt] = (floatx4)0.0f;
    }

    const int mflag = *flag;
    const u16* kb = qkv + (size_t)(b * 2048) * 3072 + 1024 + h * 64;
    const u16* vg = vT + (size_t)bh * 131072;

    // per-thread staging coordinates: chunks t and t+256 (row += 32, same seg)
    const int r0 = t >> 3, s0 = (t & 7) * 8;
    const u16* kp0 = kb + (size_t)r0 * 3072 + s0;
    const u16* kp1 = kb + (size_t)(r0 + 32) * 3072 + s0;
    const u16* vp0 = vg + (size_t)r0 * 2048 + s0;
    const u16* vp1 = vg + (size_t)(r0 + 32) * 2048 + s0;

    // prefetch tile 0 into named registers
    uint4 kr0 = *(const uint4*)(kp0);
    uint4 kr1 = *(const uint4*)(kp1);
    uint4 vr0 = *(const uint4*)(vp0);
    uint4 vr1 = *(const uint4*)(vp1);

    for (int kv0 = 0; kv0 < 2048; kv0 += 64) {
        __syncthreads();                       // all waves done reading prev Ks/Vs
        *(uint4*)&Ks[r0][s0]      = kr0;
        *(uint4*)&Ks[r0 + 32][s0] = kr1;
        *(uint4*)&Vs[r0][s0]      = vr0;
        *(uint4*)&Vs[r0 + 32][s0] = vr1;
        __syncthreads();
        if (kv0 + 64 < 2048) {                 // uniform branch; loads overlap compute
            size_t ko = (size_t)(kv0 + 64) * 3072;
            int    vo = kv0 + 64;
            kr0 = *(const uint4*)(kp0 + ko);
            kr1 = *(const uint4*)(kp1 + ko);
            vr0 = *(const uint4*)(vp0 + vo);
            vr1 = *(const uint4*)(vp1 + vo);
        }

        // S^T = K Q^T per 16-kv block; lane: q col = wm+mt*16+ln, kv = nt*16+quad*4+r.
        for (int nt = 0; nt < 4; nt++) {
            floatx4 sa0 = (floatx4)0.0f, sa1 = (floatx4)0.0f;
            for (int ks = 0; ks < 2; ks++) {
                short8 kf = *(const short8*)&Ks[nt * 16 + ln][ks * 32 + quad * 8];
                sa0 = __builtin_amdgcn_mfma_f32_16x16x32_bf16(kf, qf[0][ks], sa0, 0, 0, 0);
                sa1 = __builtin_amdgcn_mfma_f32_16x16x32_bf16(kf, qf[1][ks], sa1, 0, 0, 0);
            }
            if (mflag) {
                for (int r = 0; r < 4; r++) {
                    int kc = kv0 + nt * 16 + quad * 4 + r;
                    sa0[r] += mask[(size_t)(q0 + wm + ln) * 2048 + kc] * LOG2E;
                    sa1[r] += mask[(size_t)(q0 + wm + 16 + ln) * 2048 + kc] * LOG2E;
                }
            }
            // P = exp2(min(S,80)): 4 contiguous kv of one q row -> single b64 store
            {
                uint2 w;
                w.x = pk2(__builtin_amdgcn_exp2f(fminf(sa0[0], 80.0f)),
                          __builtin_amdgcn_exp2f(fminf(sa0[1], 80.0f)));
                w.y = pk2(__builtin_amdgcn_exp2f(fminf(sa0[2], 80.0f)),
                          __builtin_amdgcn_exp2f(fminf(sa0[3], 80.0f)));
                *(uint2*)&QPs[wm + ln][nt * 16 + quad * 4] = w;
            }
            {
                uint2 w;
                w.x = pk2(__builtin_amdgcn_exp2f(fminf(sa1[0], 80.0f)),
                          __builtin_amdgcn_exp2f(fminf(sa1[1], 80.0f)));
                w.y = pk2(__builtin_amdgcn_exp2f(fminf(sa1[2], 80.0f)),
                          __builtin_amdgcn_exp2f(fminf(sa1[3], 80.0f)));
                *(uint2*)&QPs[wm + 16 + ln][nt * 16 + quad * 4] = w;
            }
        }

        // O += P V ; l += P·1  (V fragments shared across both m-tiles)
        for (int ks = 0; ks < 2; ks++) {
            short8 a0 = *(const short8*)&QPs[wm + ln][ks * 32 + quad * 8];
            short8 a1 = *(const short8*)&QPs[wm + 16 + ln][ks * 32 + quad * 8];
            acc_l[0] = __builtin_amdgcn_mfma_f32_16x16x32_bf16(a0, ones_f, acc_l[0], 0, 0, 0);
            acc_l[1] = __builtin_amdgcn_mfma_f32_16x16x32_bf16(a1, ones_f, acc_l[1], 0, 0, 0);
            for (int dt = 0; dt < 4; dt++) {
                short8 bfr = *(const short8*)&Vs[dt * 16 + ln][ks * 32 + quad * 8];
                acc_o[0][dt] = __builtin_amdgcn_mfma_f32_16x16x32_bf16(a0, bfr, acc_o[0][dt], 0, 0, 0);
                acc_o[1][dt] = __builtin_amdgcn_mfma_f32_16x16x32_bf16(a1, bfr, acc_o[1][dt], 0, 0, 0);
            }
        }
    }

    // write O -> o[b, s, h, d] bf16 (row stride 1024)
    u16* ob = o + (size_t)(b * 2048 + q0) * 1024 + h * 64;
    for (int mt = 0; mt < 2; mt++) {
        for (int r = 0; r < 4; r++) {
            float inv = 1.0f / acc_l[mt][r];
            int row = wm + mt * 16 + quad * 4 + r;
            for (int dt = 0; dt < 4; dt++)
                ob[(size_t)row * 1024 + dt * 16 + ln] = f2b(acc_o[mt][dt][r] * inv);
        }
    }
}

extern "C" void kernel_launch(void* const* d_in, const int* in_sizes, int n_in,
                              void* d_out, int out_size, void* d_ws, size_t ws_size,
                              hipStream_t stream) {
    const float* inp    = (const float*)d_in[0];
    const float* mask   = (const float*)d_in[1];
    const float* rms_s  = (const float*)d_in[2];
    const float* Wq     = (const float*)d_in[3];
    const float* bq     = (const float*)d_in[4];
    const float* Wk     = (const float*)d_in[5];
    const float* bk     = (const float*)d_in[6];
    const float* Wv     = (const float*)d_in[7];
    const float* bv     = (const float*)d_in[8];
    const float* pds    = (const float*)d_in[9];
    const float* Wpost  = (const float*)d_in[10];
    const float* bpost  = (const float*)d_in[11];
    const float* ln_s   = (const float*)d_in[12];
    const float* ln_b   = (const float*)d_in[13];
    const float* W1     = (const float*)d_in[14];
    const float* b1     = (const float*)d_in[15];
    const float* W2     = (const float*)d_in[16];
    const float* b2     = (const float*)d_in[17];
    float* out = (float*)d_out;

    char* w = (char*)d_ws;
    const size_t MB = 1u << 20;
    u16* W1b   = (u16*)(w + 0 * MB);      // [0,8)
    u16* W2b   = (u16*)(w + 8 * MB);      // [8,16)
    u16* qkv   = (u16*)(w + 16 * MB);     // [16,64) -> f1 [16,80)
    u16* x     = (u16*)(w + 64 * MB);     // [64,80) -> o
    u16* o     = (u16*)(w + 64 * MB);
    u16* Wqkvb = (u16*)(w + 80 * MB);     // [80,86)
    u16* Wpb   = (u16*)(w + 86 * MB);     // [86,88)
    u16* yln   = (u16*)(w + 80 * MB);     // [80,96) after Wq..p dead
    u16* vT    = (u16*)(w + 96 * MB);     // [96,112) -> hb
    u16* hb    = (u16*)(w + 96 * MB);
    u16* f1    = (u16*)(w + 16 * MB);
    int* flag  = (int*)(w + 112 * MB);

    f2b_all_k<<<12288, 256, 0, stream>>>(Wq, Wk, Wv, Wpost, W1, W2, Wqkvb, Wpb, W1b, W2b, flag);
    mask_any_k<<<4096, 256, 0, stream>>>(mask, flag);

    rmsnorm_k<<<8192, 256, 0, stream>>>(inp, rms_s, x);

    gemm8_qkv_k<<<dim3(12, 32), 512, 0, stream>>>(x, Wqkvb, bq, bk, bv, pds, qkv);

    transpose_v_k<<<dim3(32, 64), 256, 0, stream>>>(qkv, vT);

    attn_k<<<dim3(16, 64), 256, 0, stream>>>(qkv, vT, mask, flag, o);

    gemm8_bt_k<2, false, true><<<dim3(4, 32), 512, 0, stream>>>(o, Wpb, bpost, inp, hb, 8192, 1024, 1024);

    layernorm_k<<<8192, 256, 0, stream>>>(hb, ln_s, ln_b, yln);

    gemm8_bt_k<1, false, true><<<dim3(16, 32), 512, 0, stream>>>(yln, W1b, b1, nullptr, f1, 8192, 4096, 1024);
    gemm8_bt_k<2, true, false><<<dim3(4, 32), 512, 0, stream>>>(f1, W2b, b2, hb, out, 8192, 1024, 4096);
}

// Round 3
// 556.930 us; speedup vs baseline: 1.0785x; 1.0785x over previous
//
#include <hip/hip_runtime.h>
#include <hip/hip_bf16.h>

typedef unsigned short u16;
typedef __attribute__((ext_vector_type(8))) short short8;
typedef __attribute__((ext_vector_type(4))) float floatx4;

#define R_PDS 0.18033688f     // r_softplus_0 / sqrt(64)
#define LOG2E 1.4426950408889634f

__device__ __forceinline__ float bf2f(u16 u) {
    union { float f; unsigned int i; } c; c.i = ((unsigned int)u) << 16; return c.f;
}
__device__ __forceinline__ u16 f2b(float f) {
    union { float f; unsigned int i; } c; c.f = f;
    unsigned int r = c.i + 0x7fffu + ((c.i >> 16) & 1u);
    return (u16)(r >> 16);
}
// packed fp32x2 -> bf16x2 (RNE), lo=a hi=b
__device__ __forceinline__ unsigned int pk2(float a, float b) {
    __hip_bfloat162 h = __float22bfloat162_rn(float2{a, b});
    unsigned int u; __builtin_memcpy(&u, &h, 4); return u;
}

// async global->LDS, 16B per lane. LDS dest is wave-uniform base + lane*16.
__device__ __forceinline__ void async16(const u16* g, u16* l) {
    __builtin_amdgcn_global_load_lds(
        (const __attribute__((address_space(1))) unsigned int*)g,
        (__attribute__((address_space(3))) unsigned int*)l, 16, 0, 0);
}

// ---------------- all weight fp32->bf16 converts in ONE kernel (+flag zero) ------------
__global__ __launch_bounds__(256) void f2b_all_k(const float* __restrict__ Wq, const float* __restrict__ Wk,
                                                 const float* __restrict__ Wv, const float* __restrict__ Wp,
                                                 const float* __restrict__ W1, const float* __restrict__ W2,
                                                 u16* __restrict__ Wqkvb, u16* __restrict__ Wpb,
                                                 u16* __restrict__ W1b,  u16* __restrict__ W2b,
                                                 int* flag) {
    int bid = blockIdx.x;
    if (bid == 0 && threadIdx.x == 0) *flag = 0;
    const float* src; u16* dst; int off;
    if      (bid < 1024) { src = Wq; dst = Wqkvb;                off = bid; }
    else if (bid < 2048) { src = Wk; dst = Wqkvb + 1024 * 1024;  off = bid - 1024; }
    else if (bid < 3072) { src = Wv; dst = Wqkvb + 2048 * 1024;  off = bid - 2048; }
    else if (bid < 4096) { src = Wp; dst = Wpb;                  off = bid - 3072; }
    else if (bid < 8192) { src = W1; dst = W1b;                  off = bid - 4096; }
    else                 { src = W2; dst = W2b;                  off = bid - 8192; }
    int i = off * 256 + threadIdx.x;
    float4 v = ((const float4*)src)[i];
    uint2 w; w.x = pk2(v.x, v.y); w.y = pk2(v.z, v.w);
    ((uint2*)dst)[i] = w;
}

__global__ __launch_bounds__(256) void mask_any_k(const float* __restrict__ mask, int* flag) {
    int i = blockIdx.x * 256 + threadIdx.x;
    uint4 u = ((const uint4*)mask)[i];
    unsigned int v = (u.x | u.y | u.z | u.w) & 0x7fffffffu;
    if (v) atomicOr(flag, 1);
}

// ---------------- RMSNorm (row = 1024 fp32) -> bf16 ----------------
__global__ __launch_bounds__(256) void rmsnorm_k(const float* __restrict__ in,
                                                 const float* __restrict__ gscale,
                                                 u16* __restrict__ out) {
    int row = blockIdx.x;
    int t = threadIdx.x, lane = t & 63, wave = t >> 6;
    const float* x = in + (size_t)row * 1024;
    float4 v = *(const float4*)(x + t * 4);
    float ss = v.x*v.x + v.y*v.y + v.z*v.z + v.w*v.w;
    for (int o = 1; o < 64; o <<= 1) ss += __shfl_xor(ss, o, 64);
    __shared__ float red[4];
    if (lane == 0) red[wave] = ss;
    __syncthreads();
    float tot = red[0] + red[1] + red[2] + red[3];
    float inv = rsqrtf(tot * (1.0f / 1024.0f) + 1e-6f);
    float4 s = *(const float4*)(gscale + t * 4);
    uint2 w;
    w.x = pk2(v.x * inv * s.x, v.y * inv * s.y);
    w.y = pk2(v.z * inv * s.z, v.w * inv * s.w);
    *(uint2*)(out + (size_t)row * 1024 + t * 4) = w;
}

// ---------------- LayerNorm (row = 1024 bf16 in, eff scale = 1+s) -> bf16 ----------------
__global__ __launch_bounds__(256) void layernorm_k(const u16* __restrict__ in,
                                                   const float* __restrict__ gs,
                                                   const float* __restrict__ gb,
                                                   u16* __restrict__ out) {
    int row = blockIdx.x;
    int t = threadIdx.x, lane = t & 63, wave = t >> 6;
    const u16* x = in + (size_t)row * 1024;
    uint2 u = *(const uint2*)(x + t * 4);
    float v0 = bf2f((u16)(u.x & 0xffff)), v1 = bf2f((u16)(u.x >> 16));
    float v2 = bf2f((u16)(u.y & 0xffff)), v3 = bf2f((u16)(u.y >> 16));
    float s1 = v0 + v1 + v2 + v3;
    float s2 = v0*v0 + v1*v1 + v2*v2 + v3*v3;
    for (int o = 1; o < 64; o <<= 1) { s1 += __shfl_xor(s1, o, 64); s2 += __shfl_xor(s2, o, 64); }
    __shared__ float r1[4], r2[4];
    if (lane == 0) { r1[wave] = s1; r2[wave] = s2; }
    __syncthreads();
    float mean = (r1[0] + r1[1] + r1[2] + r1[3]) * (1.0f / 1024.0f);
    float var  = (r2[0] + r2[1] + r2[2] + r2[3]) * (1.0f / 1024.0f) - mean * mean;
    var = fmaxf(var, 0.0f);
    float inv = rsqrtf(var + 1e-6f);
    float4 sc = *(const float4*)(gs + t * 4);
    float4 bb = *(const float4*)(gb + t * 4);
    uint2 w;
    w.x = pk2((v0 - mean) * inv * (1.0f + sc.x) + bb.x,
              (v1 - mean) * inv * (1.0f + sc.y) + bb.y);
    w.y = pk2((v2 - mean) * inv * (1.0f + sc.z) + bb.z,
              (v3 - mean) * inv * (1.0f + sc.w) + bb.w);
    *(uint2*)(out + (size_t)row * 1024 + t * 4) = w;
}

// XCD-aware bijective swizzle of the linear block id (nwg % 8 == 0 at all call sites)
__device__ __forceinline__ void xcd_swizzle(int& bx, int& by) {
    int gx = gridDim.x, nwg = gx * gridDim.y;
    int lin = blockIdx.y * gx + blockIdx.x;
    int swz = (lin & 7) * (nwg >> 3) + (lin >> 3);
    bx = swz % gx; by = swz / gx;
}

// ================= 8-phase 256x256 GEMM core (T1+T2+T3+T4+T5) =================
// BM=BN=256, BK=64, 512 thr = 8 waves (2M x 4N); per-wave C = 128x64 (8x4 frags).
// LDS 128 KiB: 2 bufs x {A0,A1,B0,B1} half-tiles (128 rows x 64 k bf16 = 16 KB).
__device__ __forceinline__ void gemm8_core(const u16* __restrict__ A, const u16* __restrict__ B,
                                           int K, int NG, int m0, int n0,
                                           u16* lds, floatx4 (&acc)[8][4]) {
    const int t = threadIdx.x, wave = t >> 6, lane = t & 63;
    const int quad = lane >> 4, ln = lane & 15;
    const int wave_m = wave >> 2, wave_n = wave & 3;

    const int rowS = t >> 3;                                   // 0..63
    const int srcb = ((t & 7) * 16) ^ (((t >> 3) & 7) << 4);   // swizzled in-row byte
    const u16* Ab = A + (size_t)(m0 + rowS) * K + (srcb >> 1);
    const u16* Bb = B + (size_t)(n0 + rowS) * K + (srcb >> 1);
    const size_t rstep = (size_t)64 * K;                       // chunk-2 rows
    const size_t hstep = (size_t)128 * K;                      // half-1 rows
    const int ldw = wave * 512;                                // u16 wave slice in half

    #define STAGE_A8(buf, h, kt) do { \
        u16* _l = lds + (buf) * 32768 + (h) * 8192 + ldw; \
        const u16* _g = Ab + (size_t)(h) * hstep + (kt); \
        async16(_g, _l); async16(_g + rstep, _l + 4096); } while (0)
    #define STAGE_B8(buf, h, kt) do { \
        u16* _l = lds + (buf) * 32768 + 16384 + (h) * 8192 + ldw; \
        const u16* _g = Bb + (size_t)(h) * hstep + (kt); \
        async16(_g, _l); async16(_g + rstep, _l + 4096); } while (0)

    #define RD8(base, lr, ks) \
        (*(const short8*)((base) + (lr) * 64 + ((((ks) * 64 + quad * 16) ^ (((lr) & 7) << 4)) >> 1)))

    // prologue: T0 fully + B halves of T1; drain T0, keep T1.B in flight
    STAGE_B8(0, 0, 0); STAGE_B8(0, 1, 0);
    STAGE_A8(0, 0, 0); STAGE_A8(0, 1, 0);
    if (NG > 1) {
        STAGE_B8(1, 0, 64); STAGE_B8(1, 1, 64);
        asm volatile("s_waitcnt vmcnt(4)" ::: "memory");
    } else {
        asm volatile("s_waitcnt vmcnt(0)" ::: "memory");
    }
    __builtin_amdgcn_s_barrier();

    for (int g = 0; g < NG; ++g) {
        const int cur = g & 1;
        const u16* aH = lds + cur * 32768 + wave_m * 8192;
        const u16* bH = lds + cur * 32768 + 16384 + (wave_n >> 1) * 8192;
        const int lrB = (wave_n & 1) * 64;
        short8 bf[4][2];
        #pragma unroll
        for (int q = 0; q < 4; ++q) {
            short8 af[2][2];
            #pragma unroll
            for (int mt = 0; mt < 2; ++mt)
                #pragma unroll
                for (int ks = 0; ks < 2; ++ks)
                    af[mt][ks] = RD8(aH, q * 32 + mt * 16 + ln, ks);
            if (q == 0) {
                #pragma unroll
                for (int nt = 0; nt < 4; ++nt)
                    #pragma unroll
                    for (int ks = 0; ks < 2; ++ks)
                        bf[nt][ks] = RD8(bH, lrB + nt * 16 + ln, ks);
            }
            if (q == 0 && g + 1 < NG) STAGE_A8(cur ^ 1, 0, (g + 1) * 64);
            if (q == 1 && g + 1 < NG) STAGE_A8(cur ^ 1, 1, (g + 1) * 64);
            if (q == 2 && g + 2 < NG) STAGE_B8(cur, 0, (g + 2) * 64);
            if (q == 3 && g + 2 < NG) STAGE_B8(cur, 1, (g + 2) * 64);
            __builtin_amdgcn_s_barrier();
            asm volatile("s_waitcnt lgkmcnt(0)" ::: "memory");
            __builtin_amdgcn_sched_barrier(0);
            __builtin_amdgcn_s_setprio(1);
            #pragma unroll
            for (int ks = 0; ks < 2; ++ks)
                #pragma unroll
                for (int mt = 0; mt < 2; ++mt)
                    #pragma unroll
                    for (int nt = 0; nt < 4; ++nt)
                        acc[q * 2 + mt][nt] = __builtin_amdgcn_mfma_f32_16x16x32_bf16(
                            af[mt][ks], bf[nt][ks], acc[q * 2 + mt][nt], 0, 0, 0);
            __builtin_amdgcn_s_setprio(0);
            __builtin_amdgcn_sched_barrier(0);
            if (q == 3 && g + 1 < NG) {
                if (g + 2 < NG) asm volatile("s_waitcnt vmcnt(4)" ::: "memory");
                else            asm volatile("s_waitcnt vmcnt(0)" ::: "memory");
            }
            __builtin_amdgcn_s_barrier();
        }
    }
    #undef STAGE_A8
    #undef STAGE_B8
    #undef RD8
}

// ================= 8-phase 128x256 GEMM core (full-GPU grids for skinny N) ============
// BM=128, BN=256, BK=64, 512 thr = 8 waves (2M x 4N); per-wave C = 64x64 (4x4 frags).
// LDS 96 KiB: 2 bufs x (A 16 KB + B 32 KB); halves = 64 rows x 64 k = 8 KB (1 DMA instr
// per 512-thr block). 2 MFMA-phases of 16 per K-step. Staging: A(g+1) at q0 (into dead
// buffer region); B(g+2) at q1 (cur buffer B is only read at q0, confirmed by q0's
// closing barrier). vmcnt(4) at q1-end drains B(g+1)+A(g+1), keeps B(g+2) in flight.
__device__ __forceinline__ void gemm8h_core(const u16* __restrict__ A, const u16* __restrict__ B,
                                            int K, int NG, int m0, int n0,
                                            u16* lds, floatx4 (&acc)[4][4]) {
    const int t = threadIdx.x, wave = t >> 6, lane = t & 63;
    const int quad = lane >> 4, ln = lane & 15;
    const int wm = (wave >> 2) * 64, wn = (wave & 3) * 64;

    const int rowS = t >> 3;                                   // 0..63
    const int srcb = ((t & 7) * 16) ^ (((t >> 3) & 7) << 4);   // swizzled in-row byte
    const u16* Ab = A + (size_t)(m0 + rowS) * K + (srcb >> 1);
    const u16* Bb = B + (size_t)(n0 + rowS) * K + (srcb >> 1);
    const size_t hstep = (size_t)64 * K;                       // half = 64 rows
    const int ldw = wave * 512;

    #define STAGE_AH(buf, h, kt) \
        async16(Ab + (size_t)(h) * hstep + (kt), lds + (buf) * 24576 + (h) * 4096 + ldw)
    #define STAGE_BH(buf, h, kt) \
        async16(Bb + (size_t)(h) * hstep + (kt), lds + (buf) * 24576 + 8192 + (h) * 4096 + ldw)
    #define RD8H(base, lr, ks) \
        (*(const short8*)((base) + (lr) * 64 + ((((ks) * 64 + quad * 16) ^ (((lr) & 7) << 4)) >> 1)))

    // prologue: T0 (B 4 halves + A 2 halves) + B of T1; drain T0, keep T1.B in flight
    STAGE_BH(0, 0, 0); STAGE_BH(0, 1, 0); STAGE_BH(0, 2, 0); STAGE_BH(0, 3, 0);
    STAGE_AH(0, 0, 0); STAGE_AH(0, 1, 0);
    if (NG > 1) {
        STAGE_BH(1, 0, 64); STAGE_BH(1, 1, 64); STAGE_BH(1, 2, 64); STAGE_BH(1, 3, 64);
        asm volatile("s_waitcnt vmcnt(4)" ::: "memory");
    } else {
        asm volatile("s_waitcnt vmcnt(0)" ::: "memory");
    }
    __builtin_amdgcn_s_barrier();

    for (int g = 0; g < NG; ++g) {
        const int cur = g & 1;
        const u16* aB = lds + cur * 24576;
        const u16* bB = lds + cur * 24576 + 8192;
        short8 bf[4][2];
        #pragma unroll
        for (int q = 0; q < 2; ++q) {
            short8 af[2][2];
            #pragma unroll
            for (int mt = 0; mt < 2; ++mt)
                #pragma unroll
                for (int ks = 0; ks < 2; ++ks)
                    af[mt][ks] = RD8H(aB, wm + (q * 2 + mt) * 16 + ln, ks);
            if (q == 0) {
                #pragma unroll
                for (int nt = 0; nt < 4; ++nt)
                    #pragma unroll
                    for (int ks = 0; ks < 2; ++ks)
                        bf[nt][ks] = RD8H(bB, wn + nt * 16 + ln, ks);
            }
            if (q == 0 && g + 1 < NG) {
                STAGE_AH(cur ^ 1, 0, (g + 1) * 64); STAGE_AH(cur ^ 1, 1, (g + 1) * 64);
            }
            if (q == 1 && g + 2 < NG) {
                STAGE_BH(cur, 0, (g + 2) * 64); STAGE_BH(cur, 1, (g + 2) * 64);
                STAGE_BH(cur, 2, (g + 2) * 64); STAGE_BH(cur, 3, (g + 2) * 64);
            }
            __builtin_amdgcn_s_barrier();
            asm volatile("s_waitcnt lgkmcnt(0)" ::: "memory");
            __builtin_amdgcn_sched_barrier(0);
            __builtin_amdgcn_s_setprio(1);
            #pragma unroll
            for (int ks = 0; ks < 2; ++ks)
                #pragma unroll
                for (int mt = 0; mt < 2; ++mt)
                    #pragma unroll
                    for (int nt = 0; nt < 4; ++nt)
                        acc[q * 2 + mt][nt] = __builtin_amdgcn_mfma_f32_16x16x32_bf16(
                            af[mt][ks], bf[nt][ks], acc[q * 2 + mt][nt], 0, 0, 0);
            __builtin_amdgcn_s_setprio(0);
            __builtin_amdgcn_sched_barrier(0);
            if (q == 1 && g + 1 < NG) {
                if (g + 2 < NG) asm volatile("s_waitcnt vmcnt(4)" ::: "memory");
                else            asm volatile("s_waitcnt vmcnt(0)" ::: "memory");
            }
            __builtin_amdgcn_s_barrier();
        }
    }
    #undef STAGE_AH
    #undef STAGE_BH
    #undef RD8H
}

// ---------------- 256x256 8-phase GEMM (W1) ----------------
template <int EPI, bool OUTF32, bool RESF32>
__global__ __launch_bounds__(512, 2) void gemm8_bt_k(const u16* __restrict__ A,
                                                     const u16* __restrict__ B,
                                                     const float* __restrict__ bias,
                                                     const void* __restrict__ res,
                                                     void* __restrict__ Cv,
                                                     int M, int N, int K) {
    __shared__ __align__(16) u16 lds[65536];   // 128 KiB
    int bx, by; xcd_swizzle(bx, by);
    const int m0 = by * 256, n0 = bx * 256;
    const int t = threadIdx.x, wave = t >> 6, lane = t & 63;
    const int quad = lane >> 4, ln = lane & 15;
    const int wm = (wave >> 2) * 128, wn = (wave & 3) * 64;

    floatx4 acc[8][4];
    #pragma unroll
    for (int mf = 0; mf < 8; mf++)
        #pragma unroll
        for (int nf = 0; nf < 4; nf++) acc[mf][nf] = (floatx4)0.0f;

    gemm8_core(A, B, K, K >> 6, m0, n0, lds, acc);

    #pragma unroll
    for (int nf = 0; nf < 4; nf++) {
        int col = n0 + wn + nf * 16 + ln;
        float bv = bias[col];
        #pragma unroll
        for (int mf = 0; mf < 8; mf++) {
            int row = m0 + wm + mf * 16 + quad * 4;
            #pragma unroll
            for (int r = 0; r < 4; r++) {
                float v = acc[mf][nf][r] + bv;
                if (EPI == 1) v = fmaxf(v, 0.0f);
                if (EPI == 2) {
                    if (RESF32) v += ((const float*)res)[(size_t)(row + r) * N + col];
                    else        v += bf2f(((const u16*)res)[(size_t)(row + r) * N + col]);
                }
                if (OUTF32) ((float*)Cv)[(size_t)(row + r) * N + col] = v;
                else        ((u16*)Cv)[(size_t)(row + r) * N + col] = f2b(v);
            }
        }
    }
}

// ---------------- 128x256 8-phase GEMM (Wpost, W2) ----------------
template <int EPI, bool OUTF32, bool RESF32>
__global__ __launch_bounds__(512, 2) void gemm8h_bt_k(const u16* __restrict__ A,
                                                      const u16* __restrict__ B,
                                                      const float* __restrict__ bias,
                                                      const void* __restrict__ res,
                                                      void* __restrict__ Cv,
                                                      int M, int N, int K) {
    __shared__ __align__(16) u16 lds[49152];   // 96 KiB
    int bx, by; xcd_swizzle(bx, by);
    const int m0 = by * 128, n0 = bx * 256;
    const int t = threadIdx.x, wave = t >> 6, lane = t & 63;
    const int quad = lane >> 4, ln = lane & 15;
    const int wm = (wave >> 2) * 64, wn = (wave & 3) * 64;

    floatx4 acc[4][4];
    #pragma unroll
    for (int mf = 0; mf < 4; mf++)
        #pragma unroll
        for (int nf = 0; nf < 4; nf++) acc[mf][nf] = (floatx4)0.0f;

    gemm8h_core(A, B, K, K >> 6, m0, n0, lds, acc);

    #pragma unroll
    for (int nf = 0; nf < 4; nf++) {
        int col = n0 + wn + nf * 16 + ln;
        float bv = bias[col];
        #pragma unroll
        for (int mf = 0; mf < 4; mf++) {
            int row = m0 + wm + mf * 16 + quad * 4;
            #pragma unroll
            for (int r = 0; r < 4; r++) {
                float v = acc[mf][nf][r] + bv;
                if (EPI == 1) v = fmaxf(v, 0.0f);
                if (EPI == 2) {
                    if (RESF32) v += ((const float*)res)[(size_t)(row + r) * N + col];
                    else        v += bf2f(((const u16*)res)[(size_t)(row + r) * N + col]);
                }
                if (OUTF32) ((float*)Cv)[(size_t)(row + r) * N + col] = v;
                else        ((u16*)Cv)[(size_t)(row + r) * N + col] = f2b(v);
            }
        }
    }
}

// ---------------- 128x256 fused QKV GEMM: q cols scaled by softplus(pds)*LOG2E --------
__global__ __launch_bounds__(512, 2) void gemm8h_qkv_k(const u16* __restrict__ A,
                                                       const u16* __restrict__ B,
                                                       const float* __restrict__ bq,
                                                       const float* __restrict__ bk,
                                                       const float* __restrict__ bv,
                                                       const float* __restrict__ pds,
                                                       u16* __restrict__ C) {
    const int K = 1024, N = 3072;
    __shared__ __align__(16) u16 lds[49152];
    int bx, by; xcd_swizzle(bx, by);
    const int m0 = by * 128, n0 = bx * 256;
    const int t = threadIdx.x, wave = t >> 6, lane = t & 63;
    const int quad = lane >> 4, ln = lane & 15;
    const int wm = (wave >> 2) * 64, wn = (wave & 3) * 64;

    floatx4 acc[4][4];
    #pragma unroll
    for (int mf = 0; mf < 4; mf++)
        #pragma unroll
        for (int nf = 0; nf < 4; nf++) acc[mf][nf] = (floatx4)0.0f;

    gemm8h_core(A, B, K, K >> 6, m0, n0, lds, acc);

    #pragma unroll
    for (int nf = 0; nf < 4; nf++) {
        int col = n0 + wn + nf * 16 + ln;
        float bv_, sc = 1.0f;
        if (col < 1024) {
            bv_ = bq[col];
            float xp = pds[col & 63];
            float sp = (xp > 20.0f) ? xp : log1pf(__expf(xp));
            sc = R_PDS * sp * LOG2E;            // fold log2(e): attn uses exp2
        } else if (col < 2048) bv_ = bk[col - 1024];
        else                   bv_ = bv[col - 2048];
        #pragma unroll
        for (int mf = 0; mf < 4; mf++) {
            int row = m0 + wm + mf * 16 + quad * 4;
            #pragma unroll
            for (int r = 0; r < 4; r++)
                C[(size_t)(row + r) * N + col] = f2b((acc[mf][nf][r] + bv_) * sc);
        }
    }
}

// ---------------- V transpose: qkv v-part -> vT[bh][d][s] ----------------
__global__ __launch_bounds__(256) void transpose_v_k(const u16* __restrict__ qkv, u16* __restrict__ vT) {
    __shared__ u16 tile[64][65];
    int st = blockIdx.x, bh = blockIdx.y;
    int b = bh >> 4, h = bh & 15;
    const u16* vb = qkv + (size_t)(b * 2048 + st * 64) * 3072 + 2048 + h * 64;
    int t = threadIdx.x;
    for (int i = t; i < 4096; i += 256) {
        int s = i >> 6, d = i & 63;
        tile[s][d] = vb[(size_t)s * 3072 + d];
    }
    __syncthreads();
    u16* ob = vT + (size_t)bh * 131072 + st * 64;
    for (int i = t; i < 4096; i += 256) {
        int d = i >> 6, s = i & 63;
        ob[(size_t)d * 2048 + s] = tile[s][d];
    }
}

// ---------------- flash attention: 1 block = (bh, 128 q rows), BKV=64 ------------------
__global__ __launch_bounds__(256) void attn_k(const u16* __restrict__ qkv,
                                              const u16* __restrict__ vT,
                                              const float* __restrict__ mask,
                                              const int* __restrict__ flag,
                                              u16* __restrict__ o) {
    __shared__ __align__(16) u16 QPs[128][72];  // Q during setup, then P (rows wave-local)
    __shared__ __align__(16) u16 Ks[64][72];
    __shared__ __align__(16) u16 Vs[64][72];    // rows = d, cols = kv

    const int t = threadIdx.x, wave = t >> 6, lane = t & 63;
    const int quad = lane >> 4, ln = lane & 15;
    const int qt = blockIdx.x, bh = blockIdx.y;
    const int b = bh >> 4, h = bh & 15;
    const int q0 = qt * 128;
    const int wm = wave * 32;

    // stage Q tile (128 rows x 64 d; pre-scaled by softplus*log2e in QKV epilogue)
    const u16* qb = qkv + (size_t)(b * 2048 + q0) * 3072 + h * 64;
    for (int c = t; c < 1024; c += 256) {
        int row = c >> 3, seg = c & 7;
        *(uint4*)&QPs[row][seg * 8] = *(const uint4*)(qb + (size_t)row * 3072 + seg * 8);
    }
    __syncthreads();

    // hoist Q fragments (rows wm..wm+31: wave-local, same rows later P writes reuse)
    short8 qf[2][2];
    for (int mt = 0; mt < 2; mt++)
        for (int ks = 0; ks < 2; ks++)
            qf[mt][ks] = *(const short8*)&QPs[wm + mt * 16 + ln][ks * 32 + quad * 8];

    short8 ones_f;
    for (int i = 0; i < 8; i++) ones_f[i] = (short)0x3F80;   // bf16 1.0

    floatx4 acc_o[2][4], acc_l[2];
    for (int mt = 0; mt < 2; mt++) {
        acc_l[mt] = (floatx4)0.0f;
        for (int dt = 0; dt < 4; dt++) acc_o[mt][dt] = (floatx4)0.0f;
    }

    const int mflag = *flag;
    const u16* kb = qkv + (size_t)(b * 2048) * 3072 + 1024 + h * 64;
    const u16* vg = vT + (size_t)bh * 131072;

    // per-thread staging coordinates: chunks t and t+256 (row += 32, same seg)
    const int r0 = t >> 3, s0 = (t & 7) * 8;
    const u16* kp0 = kb + (size_t)r0 * 3072 + s0;
    const u16* kp1 = kb + (size_t)(r0 + 32) * 3072 + s0;
    const u16* vp0 = vg + (size_t)r0 * 2048 + s0;
    const u16* vp1 = vg + (size_t)(r0 + 32) * 2048 + s0;

    // prefetch tile 0 into named registers
    uint4 kr0 = *(const uint4*)(kp0);
    uint4 kr1 = *(const uint4*)(kp1);
    uint4 vr0 = *(const uint4*)(vp0);
    uint4 vr1 = *(const uint4*)(vp1);

    for (int kv0 = 0; kv0 < 2048; kv0 += 64) {
        __syncthreads();                       // all waves done reading prev Ks/Vs
        *(uint4*)&Ks[r0][s0]      = kr0;
        *(uint4*)&Ks[r0 + 32][s0] = kr1;
        *(uint4*)&Vs[r0][s0]      = vr0;
        *(uint4*)&Vs[r0 + 32][s0] = vr1;
        __syncthreads();
        if (kv0 + 64 < 2048) {                 // uniform branch; loads overlap compute
            size_t ko = (size_t)(kv0 + 64) * 3072;
            int    vo = kv0 + 64;
            kr0 = *(const uint4*)(kp0 + ko);
            kr1 = *(const uint4*)(kp1 + ko);
            vr0 = *(const uint4*)(vp0 + vo);
            vr1 = *(const uint4*)(vp1 + vo);
        }

        // S^T = K Q^T per 16-kv block; lane: q col = wm+mt*16+ln, kv = nt*16+quad*4+r.
        for (int nt = 0; nt < 4; nt++) {
            floatx4 sa0 = (floatx4)0.0f, sa1 = (floatx4)0.0f;
            for (int ks = 0; ks < 2; ks++) {
                short8 kf = *(const short8*)&Ks[nt * 16 + ln][ks * 32 + quad * 8];
                sa0 = __builtin_amdgcn_mfma_f32_16x16x32_bf16(kf, qf[0][ks], sa0, 0, 0, 0);
                sa1 = __builtin_amdgcn_mfma_f32_16x16x32_bf16(kf, qf[1][ks], sa1, 0, 0, 0);
            }
            if (mflag) {
                for (int r = 0; r < 4; r++) {
                    int kc = kv0 + nt * 16 + quad * 4 + r;
                    sa0[r] += mask[(size_t)(q0 + wm + ln) * 2048 + kc] * LOG2E;
                    sa1[r] += mask[(size_t)(q0 + wm + 16 + ln) * 2048 + kc] * LOG2E;
                }
            }
            // P = exp2(min(S,80)): 4 contiguous kv of one q row -> single b64 store
            {
                uint2 w;
                w.x = pk2(__builtin_amdgcn_exp2f(fminf(sa0[0], 80.0f)),
                          __builtin_amdgcn_exp2f(fminf(sa0[1], 80.0f)));
                w.y = pk2(__builtin_amdgcn_exp2f(fminf(sa0[2], 80.0f)),
                          __builtin_amdgcn_exp2f(fminf(sa0[3], 80.0f)));
                *(uint2*)&QPs[wm + ln][nt * 16 + quad * 4] = w;
            }
            {
                uint2 w;
                w.x = pk2(__builtin_amdgcn_exp2f(fminf(sa1[0], 80.0f)),
                          __builtin_amdgcn_exp2f(fminf(sa1[1], 80.0f)));
                w.y = pk2(__builtin_amdgcn_exp2f(fminf(sa1[2], 80.0f)),
                          __builtin_amdgcn_exp2f(fminf(sa1[3], 80.0f)));
                *(uint2*)&QPs[wm + 16 + ln][nt * 16 + quad * 4] = w;
            }
        }

        // O += P V ; l += P·1  (V fragments shared across both m-tiles)
        for (int ks = 0; ks < 2; ks++) {
            short8 a0 = *(const short8*)&QPs[wm + ln][ks * 32 + quad * 8];
            short8 a1 = *(const short8*)&QPs[wm + 16 + ln][ks * 32 + quad * 8];
            acc_l[0] = __builtin_amdgcn_mfma_f32_16x16x32_bf16(a0, ones_f, acc_l[0], 0, 0, 0);
            acc_l[1] = __builtin_amdgcn_mfma_f32_16x16x32_bf16(a1, ones_f, acc_l[1], 0, 0, 0);
            for (int dt = 0; dt < 4; dt++) {
                short8 bfr = *(const short8*)&Vs[dt * 16 + ln][ks * 32 + quad * 8];
                acc_o[0][dt] = __builtin_amdgcn_mfma_f32_16x16x32_bf16(a0, bfr, acc_o[0][dt], 0, 0, 0);
                acc_o[1][dt] = __builtin_amdgcn_mfma_f32_16x16x32_bf16(a1, bfr, acc_o[1][dt], 0, 0, 0);
            }
        }
    }

    // write O -> o[b, s, h, d] bf16 (row stride 1024)
    u16* ob = o + (size_t)(b * 2048 + q0) * 1024 + h * 64;
    for (int mt = 0; mt < 2; mt++) {
        for (int r = 0; r < 4; r++) {
            float inv = 1.0f / acc_l[mt][r];
            int row = wm + mt * 16 + quad * 4 + r;
            for (int dt = 0; dt < 4; dt++)
                ob[(size_t)row * 1024 + dt * 16 + ln] = f2b(acc_o[mt][dt][r] * inv);
        }
    }
}

extern "C" void kernel_launch(void* const* d_in, const int* in_sizes, int n_in,
                              void* d_out, int out_size, void* d_ws, size_t ws_size,
                              hipStream_t stream) {
    const float* inp    = (const float*)d_in[0];
    const float* mask   = (const float*)d_in[1];
    const float* rms_s  = (const float*)d_in[2];
    const float* Wq     = (const float*)d_in[3];
    const float* bq     = (const float*)d_in[4];
    const float* Wk     = (const float*)d_in[5];
    const float* bk     = (const float*)d_in[6];
    const float* Wv     = (const float*)d_in[7];
    const float* bv     = (const float*)d_in[8];
    const float* pds    = (const float*)d_in[9];
    const float* Wpost  = (const float*)d_in[10];
    const float* bpost  = (const float*)d_in[11];
    const float* ln_s   = (const float*)d_in[12];
    const float* ln_b   = (const float*)d_in[13];
    const float* W1     = (const float*)d_in[14];
    const float* b1     = (const float*)d_in[15];
    const float* W2     = (const float*)d_in[16];
    const float* b2     = (const float*)d_in[17];
    float* out = (float*)d_out;

    char* w = (char*)d_ws;
    const size_t MB = 1u << 20;
    u16* W1b   = (u16*)(w + 0 * MB);      // [0,8)
    u16* W2b   = (u16*)(w + 8 * MB);      // [8,16)
    u16* qkv   = (u16*)(w + 16 * MB);     // [16,64) -> f1 [16,80)
    u16* x     = (u16*)(w + 64 * MB);     // [64,80) -> o
    u16* o     = (u16*)(w + 64 * MB);
    u16* Wqkvb = (u16*)(w + 80 * MB);     // [80,86)
    u16* Wpb   = (u16*)(w + 86 * MB);     // [86,88)
    u16* yln   = (u16*)(w + 80 * MB);     // [80,96) after Wq..p dead
    u16* vT    = (u16*)(w + 96 * MB);     // [96,112) -> hb
    u16* hb    = (u16*)(w + 96 * MB);
    u16* f1    = (u16*)(w + 16 * MB);
    int* flag  = (int*)(w + 112 * MB);

    f2b_all_k<<<12288, 256, 0, stream>>>(Wq, Wk, Wv, Wpost, W1, W2, Wqkvb, Wpb, W1b, W2b, flag);
    mask_any_k<<<4096, 256, 0, stream>>>(mask, flag);

    rmsnorm_k<<<8192, 256, 0, stream>>>(inp, rms_s, x);

    gemm8h_qkv_k<<<dim3(12, 64), 512, 0, stream>>>(x, Wqkvb, bq, bk, bv, pds, qkv);

    transpose_v_k<<<dim3(32, 64), 256, 0, stream>>>(qkv, vT);

    attn_k<<<dim3(16, 64), 256, 0, stream>>>(qkv, vT, mask, flag, o);

    gemm8h_bt_k<2, false, true><<<dim3(4, 64), 512, 0, stream>>>(o, Wpb, bpost, inp, hb, 8192, 1024, 1024);

    layernorm_k<<<8192, 256, 0, stream>>>(hb, ln_s, ln_b, yln);

    gemm8_bt_k<1, false, true><<<dim3(16, 32), 512, 0, stream>>>(yln, W1b, b1, nullptr, f1, 8192, 4096, 1024);
    gemm8h_bt_k<2, true, false><<<dim3(4, 64), 512, 0, stream>>>(f1, W2b, b2, hb, out, 8192, 1024, 4096);
}

// Round 4
// 506.205 us; speedup vs baseline: 1.1865x; 1.1002x over previous
//
#include <hip/hip_runtime.h>
#include <hip/hip_bf16.h>

typedef unsigned short u16;
typedef __attribute__((ext_vector_type(8))) short short8;
typedef __attribute__((ext_vector_type(4))) float floatx4;

#define R_PDS 0.18033688f     // r_softplus_0 / sqrt(64)
#define LOG2E 1.4426950408889634f

__device__ __forceinline__ float bf2f(u16 u) {
    union { float f; unsigned int i; } c; c.i = ((unsigned int)u) << 16; return c.f;
}
__device__ __forceinline__ u16 f2b(float f) {
    union { float f; unsigned int i; } c; c.f = f;
    unsigned int r = c.i + 0x7fffu + ((c.i >> 16) & 1u);
    return (u16)(r >> 16);
}
// packed fp32x2 -> bf16x2 (RNE), lo=a hi=b
__device__ __forceinline__ unsigned int pk2(float a, float b) {
    __hip_bfloat162 h = __float22bfloat162_rn(float2{a, b});
    unsigned int u; __builtin_memcpy(&u, &h, 4); return u;
}

// async global->LDS, 16B per lane. LDS dest is wave-uniform base + lane*16.
__device__ __forceinline__ void async16(const u16* g, u16* l) {
    __builtin_amdgcn_global_load_lds(
        (const __attribute__((address_space(1))) unsigned int*)g,
        (__attribute__((address_space(3))) unsigned int*)l, 16, 0, 0);
}

// ---------------- all weight fp32->bf16 converts in ONE kernel (+flag zero) ------------
__global__ __launch_bounds__(256) void f2b_all_k(const float* __restrict__ Wq, const float* __restrict__ Wk,
                                                 const float* __restrict__ Wv, const float* __restrict__ Wp,
                                                 const float* __restrict__ W1, const float* __restrict__ W2,
                                                 u16* __restrict__ Wqkvb, u16* __restrict__ Wpb,
                                                 u16* __restrict__ W1b,  u16* __restrict__ W2b,
                                                 int* flag) {
    int bid = blockIdx.x;
    if (bid == 0 && threadIdx.x == 0) *flag = 0;
    const float* src; u16* dst; int off;
    if      (bid < 1024) { src = Wq; dst = Wqkvb;                off = bid; }
    else if (bid < 2048) { src = Wk; dst = Wqkvb + 1024 * 1024;  off = bid - 1024; }
    else if (bid < 3072) { src = Wv; dst = Wqkvb + 2048 * 1024;  off = bid - 2048; }
    else if (bid < 4096) { src = Wp; dst = Wpb;                  off = bid - 3072; }
    else if (bid < 8192) { src = W1; dst = W1b;                  off = bid - 4096; }
    else                 { src = W2; dst = W2b;                  off = bid - 8192; }
    int i = off * 256 + threadIdx.x;
    float4 v = ((const float4*)src)[i];
    uint2 w; w.x = pk2(v.x, v.y); w.y = pk2(v.z, v.w);
    ((uint2*)dst)[i] = w;
}

__global__ __launch_bounds__(256) void mask_any_k(const float* __restrict__ mask, int* flag) {
    int i = blockIdx.x * 256 + threadIdx.x;
    uint4 u = ((const uint4*)mask)[i];
    unsigned int v = (u.x | u.y | u.z | u.w) & 0x7fffffffu;
    if (v) atomicOr(flag, 1);
}

// ---------------- RMSNorm (row = 1024 fp32) -> bf16 ----------------
__global__ __launch_bounds__(256) void rmsnorm_k(const float* __restrict__ in,
                                                 const float* __restrict__ gscale,
                                                 u16* __restrict__ out) {
    int row = blockIdx.x;
    int t = threadIdx.x, lane = t & 63, wave = t >> 6;
    const float* x = in + (size_t)row * 1024;
    float4 v = *(const float4*)(x + t * 4);
    float ss = v.x*v.x + v.y*v.y + v.z*v.z + v.w*v.w;
    for (int o = 1; o < 64; o <<= 1) ss += __shfl_xor(ss, o, 64);
    __shared__ float red[4];
    if (lane == 0) red[wave] = ss;
    __syncthreads();
    float tot = red[0] + red[1] + red[2] + red[3];
    float inv = rsqrtf(tot * (1.0f / 1024.0f) + 1e-6f);
    float4 s = *(const float4*)(gscale + t * 4);
    uint2 w;
    w.x = pk2(v.x * inv * s.x, v.y * inv * s.y);
    w.y = pk2(v.z * inv * s.z, v.w * inv * s.w);
    *(uint2*)(out + (size_t)row * 1024 + t * 4) = w;
}

// ---------------- LayerNorm (row = 1024 bf16 in, eff scale = 1+s) -> bf16 ----------------
__global__ __launch_bounds__(256) void layernorm_k(const u16* __restrict__ in,
                                                   const float* __restrict__ gs,
                                                   const float* __restrict__ gb,
                                                   u16* __restrict__ out) {
    int row = blockIdx.x;
    int t = threadIdx.x, lane = t & 63, wave = t >> 6;
    const u16* x = in + (size_t)row * 1024;
    uint2 u = *(const uint2*)(x + t * 4);
    float v0 = bf2f((u16)(u.x & 0xffff)), v1 = bf2f((u16)(u.x >> 16));
    float v2 = bf2f((u16)(u.y & 0xffff)), v3 = bf2f((u16)(u.y >> 16));
    float s1 = v0 + v1 + v2 + v3;
    float s2 = v0*v0 + v1*v1 + v2*v2 + v3*v3;
    for (int o = 1; o < 64; o <<= 1) { s1 += __shfl_xor(s1, o, 64); s2 += __shfl_xor(s2, o, 64); }
    __shared__ float r1[4], r2[4];
    if (lane == 0) { r1[wave] = s1; r2[wave] = s2; }
    __syncthreads();
    float mean = (r1[0] + r1[1] + r1[2] + r1[3]) * (1.0f / 1024.0f);
    float var  = (r2[0] + r2[1] + r2[2] + r2[3]) * (1.0f / 1024.0f) - mean * mean;
    var = fmaxf(var, 0.0f);
    float inv = rsqrtf(var + 1e-6f);
    float4 sc = *(const float4*)(gs + t * 4);
    float4 bb = *(const float4*)(gb + t * 4);
    uint2 w;
    w.x = pk2((v0 - mean) * inv * (1.0f + sc.x) + bb.x,
              (v1 - mean) * inv * (1.0f + sc.y) + bb.y);
    w.y = pk2((v2 - mean) * inv * (1.0f + sc.z) + bb.z,
              (v3 - mean) * inv * (1.0f + sc.w) + bb.w);
    *(uint2*)(out + (size_t)row * 1024 + t * 4) = w;
}

// XCD-aware bijective swizzle of the linear block id (nwg % 8 == 0 at all call sites)
__device__ __forceinline__ void xcd_swizzle(int& bx, int& by) {
    int gx = gridDim.x, nwg = gx * gridDim.y;
    int lin = blockIdx.y * gx + blockIdx.x;
    int swz = (lin & 7) * (nwg >> 3) + (lin >> 3);
    bx = swz % gx; by = swz / gx;
}

// ================= 8-phase 256x256 GEMM core (T1+T2+T3+T4+T5) =================
__device__ __forceinline__ void gemm8_core(const u16* __restrict__ A, const u16* __restrict__ B,
                                           int K, int NG, int m0, int n0,
                                           u16* lds, floatx4 (&acc)[8][4]) {
    const int t = threadIdx.x, wave = t >> 6, lane = t & 63;
    const int quad = lane >> 4, ln = lane & 15;
    const int wave_m = wave >> 2, wave_n = wave & 3;

    const int rowS = t >> 3;                                   // 0..63
    const int srcb = ((t & 7) * 16) ^ (((t >> 3) & 7) << 4);   // swizzled in-row byte
    const u16* Ab = A + (size_t)(m0 + rowS) * K + (srcb >> 1);
    const u16* Bb = B + (size_t)(n0 + rowS) * K + (srcb >> 1);
    const size_t rstep = (size_t)64 * K;                       // chunk-2 rows
    const size_t hstep = (size_t)128 * K;                      // half-1 rows
    const int ldw = wave * 512;                                // u16 wave slice in half

    #define STAGE_A8(buf, h, kt) do { \
        u16* _l = lds + (buf) * 32768 + (h) * 8192 + ldw; \
        const u16* _g = Ab + (size_t)(h) * hstep + (kt); \
        async16(_g, _l); async16(_g + rstep, _l + 4096); } while (0)
    #define STAGE_B8(buf, h, kt) do { \
        u16* _l = lds + (buf) * 32768 + 16384 + (h) * 8192 + ldw; \
        const u16* _g = Bb + (size_t)(h) * hstep + (kt); \
        async16(_g, _l); async16(_g + rstep, _l + 4096); } while (0)

    #define RD8(base, lr, ks) \
        (*(const short8*)((base) + (lr) * 64 + ((((ks) * 64 + quad * 16) ^ (((lr) & 7) << 4)) >> 1)))

    // prologue: T0 fully + B halves of T1; drain T0, keep T1.B in flight
    STAGE_B8(0, 0, 0); STAGE_B8(0, 1, 0);
    STAGE_A8(0, 0, 0); STAGE_A8(0, 1, 0);
    if (NG > 1) {
        STAGE_B8(1, 0, 64); STAGE_B8(1, 1, 64);
        asm volatile("s_waitcnt vmcnt(4)" ::: "memory");
    } else {
        asm volatile("s_waitcnt vmcnt(0)" ::: "memory");
    }
    __builtin_amdgcn_s_barrier();

    for (int g = 0; g < NG; ++g) {
        const int cur = g & 1;
        const u16* aH = lds + cur * 32768 + wave_m * 8192;
        const u16* bH = lds + cur * 32768 + 16384 + (wave_n >> 1) * 8192;
        const int lrB = (wave_n & 1) * 64;
        short8 bf[4][2];
        #pragma unroll
        for (int q = 0; q < 4; ++q) {
            short8 af[2][2];
            #pragma unroll
            for (int mt = 0; mt < 2; ++mt)
                #pragma unroll
                for (int ks = 0; ks < 2; ++ks)
                    af[mt][ks] = RD8(aH, q * 32 + mt * 16 + ln, ks);
            if (q == 0) {
                #pragma unroll
                for (int nt = 0; nt < 4; ++nt)
                    #pragma unroll
                    for (int ks = 0; ks < 2; ++ks)
                        bf[nt][ks] = RD8(bH, lrB + nt * 16 + ln, ks);
            }
            if (q == 0 && g + 1 < NG) STAGE_A8(cur ^ 1, 0, (g + 1) * 64);
            if (q == 1 && g + 1 < NG) STAGE_A8(cur ^ 1, 1, (g + 1) * 64);
            if (q == 2 && g + 2 < NG) STAGE_B8(cur, 0, (g + 2) * 64);
            if (q == 3 && g + 2 < NG) STAGE_B8(cur, 1, (g + 2) * 64);
            __builtin_amdgcn_s_barrier();
            asm volatile("s_waitcnt lgkmcnt(0)" ::: "memory");
            __builtin_amdgcn_sched_barrier(0);
            __builtin_amdgcn_s_setprio(1);
            #pragma unroll
            for (int ks = 0; ks < 2; ++ks)
                #pragma unroll
                for (int mt = 0; mt < 2; ++mt)
                    #pragma unroll
                    for (int nt = 0; nt < 4; ++nt)
                        acc[q * 2 + mt][nt] = __builtin_amdgcn_mfma_f32_16x16x32_bf16(
                            af[mt][ks], bf[nt][ks], acc[q * 2 + mt][nt], 0, 0, 0);
            __builtin_amdgcn_s_setprio(0);
            __builtin_amdgcn_sched_barrier(0);
            if (q == 3 && g + 1 < NG) {
                if (g + 2 < NG) asm volatile("s_waitcnt vmcnt(4)" ::: "memory");
                else            asm volatile("s_waitcnt vmcnt(0)" ::: "memory");
            }
            __builtin_amdgcn_s_barrier();
        }
    }
    #undef STAGE_A8
    #undef STAGE_B8
    #undef RD8
}

// ================= 8-phase 128x256 GEMM core (full-GPU grids for skinny N) ============
__device__ __forceinline__ void gemm8h_core(const u16* __restrict__ A, const u16* __restrict__ B,
                                            int K, int NG, int m0, int n0,
                                            u16* lds, floatx4 (&acc)[4][4]) {
    const int t = threadIdx.x, wave = t >> 6, lane = t & 63;
    const int quad = lane >> 4, ln = lane & 15;
    const int wm = (wave >> 2) * 64, wn = (wave & 3) * 64;

    const int rowS = t >> 3;                                   // 0..63
    const int srcb = ((t & 7) * 16) ^ (((t >> 3) & 7) << 4);   // swizzled in-row byte
    const u16* Ab = A + (size_t)(m0 + rowS) * K + (srcb >> 1);
    const u16* Bb = B + (size_t)(n0 + rowS) * K + (srcb >> 1);
    const size_t hstep = (size_t)64 * K;                       // half = 64 rows
    const int ldw = wave * 512;

    #define STAGE_AH(buf, h, kt) \
        async16(Ab + (size_t)(h) * hstep + (kt), lds + (buf) * 24576 + (h) * 4096 + ldw)
    #define STAGE_BH(buf, h, kt) \
        async16(Bb + (size_t)(h) * hstep + (kt), lds + (buf) * 24576 + 8192 + (h) * 4096 + ldw)
    #define RD8H(base, lr, ks) \
        (*(const short8*)((base) + (lr) * 64 + ((((ks) * 64 + quad * 16) ^ (((lr) & 7) << 4)) >> 1)))

    // prologue: T0 (B 4 halves + A 2 halves) + B of T1; drain T0, keep T1.B in flight
    STAGE_BH(0, 0, 0); STAGE_BH(0, 1, 0); STAGE_BH(0, 2, 0); STAGE_BH(0, 3, 0);
    STAGE_AH(0, 0, 0); STAGE_AH(0, 1, 0);
    if (NG > 1) {
        STAGE_BH(1, 0, 64); STAGE_BH(1, 1, 64); STAGE_BH(1, 2, 64); STAGE_BH(1, 3, 64);
        asm volatile("s_waitcnt vmcnt(4)" ::: "memory");
    } else {
        asm volatile("s_waitcnt vmcnt(0)" ::: "memory");
    }
    __builtin_amdgcn_s_barrier();

    for (int g = 0; g < NG; ++g) {
        const int cur = g & 1;
        const u16* aB = lds + cur * 24576;
        const u16* bB = lds + cur * 24576 + 8192;
        short8 bf[4][2];
        #pragma unroll
        for (int q = 0; q < 2; ++q) {
            short8 af[2][2];
            #pragma unroll
            for (int mt = 0; mt < 2; ++mt)
                #pragma unroll
                for (int ks = 0; ks < 2; ++ks)
                    af[mt][ks] = RD8H(aB, wm + (q * 2 + mt) * 16 + ln, ks);
            if (q == 0) {
                #pragma unroll
                for (int nt = 0; nt < 4; ++nt)
                    #pragma unroll
                    for (int ks = 0; ks < 2; ++ks)
                        bf[nt][ks] = RD8H(bB, wn + nt * 16 + ln, ks);
            }
            if (q == 0 && g + 1 < NG) {
                STAGE_AH(cur ^ 1, 0, (g + 1) * 64); STAGE_AH(cur ^ 1, 1, (g + 1) * 64);
            }
            if (q == 1 && g + 2 < NG) {
                STAGE_BH(cur, 0, (g + 2) * 64); STAGE_BH(cur, 1, (g + 2) * 64);
                STAGE_BH(cur, 2, (g + 2) * 64); STAGE_BH(cur, 3, (g + 2) * 64);
            }
            __builtin_amdgcn_s_barrier();
            asm volatile("s_waitcnt lgkmcnt(0)" ::: "memory");
            __builtin_amdgcn_sched_barrier(0);
            __builtin_amdgcn_s_setprio(1);
            #pragma unroll
            for (int ks = 0; ks < 2; ++ks)
                #pragma unroll
                for (int mt = 0; mt < 2; ++mt)
                    #pragma unroll
                    for (int nt = 0; nt < 4; ++nt)
                        acc[q * 2 + mt][nt] = __builtin_amdgcn_mfma_f32_16x16x32_bf16(
                            af[mt][ks], bf[nt][ks], acc[q * 2 + mt][nt], 0, 0, 0);
            __builtin_amdgcn_s_setprio(0);
            __builtin_amdgcn_sched_barrier(0);
            if (q == 1 && g + 1 < NG) {
                if (g + 2 < NG) asm volatile("s_waitcnt vmcnt(4)" ::: "memory");
                else            asm volatile("s_waitcnt vmcnt(0)" ::: "memory");
            }
            __builtin_amdgcn_s_barrier();
        }
    }
    #undef STAGE_AH
    #undef STAGE_BH
    #undef RD8H
}

// ---------------- 256x256 8-phase GEMM (W1) ----------------
template <int EPI, bool OUTF32, bool RESF32>
__global__ __launch_bounds__(512, 2) void gemm8_bt_k(const u16* __restrict__ A,
                                                     const u16* __restrict__ B,
                                                     const float* __restrict__ bias,
                                                     const void* __restrict__ res,
                                                     void* __restrict__ Cv,
                                                     int M, int N, int K) {
    __shared__ __align__(16) u16 lds[65536];   // 128 KiB
    int bx, by; xcd_swizzle(bx, by);
    const int m0 = by * 256, n0 = bx * 256;
    const int t = threadIdx.x, wave = t >> 6, lane = t & 63;
    const int quad = lane >> 4, ln = lane & 15;
    const int wm = (wave >> 2) * 128, wn = (wave & 3) * 64;

    floatx4 acc[8][4];
    #pragma unroll
    for (int mf = 0; mf < 8; mf++)
        #pragma unroll
        for (int nf = 0; nf < 4; nf++) acc[mf][nf] = (floatx4)0.0f;

    gemm8_core(A, B, K, K >> 6, m0, n0, lds, acc);

    #pragma unroll
    for (int nf = 0; nf < 4; nf++) {
        int col = n0 + wn + nf * 16 + ln;
        float bv = bias[col];
        #pragma unroll
        for (int mf = 0; mf < 8; mf++) {
            int row = m0 + wm + mf * 16 + quad * 4;
            #pragma unroll
            for (int r = 0; r < 4; r++) {
                float v = acc[mf][nf][r] + bv;
                if (EPI == 1) v = fmaxf(v, 0.0f);
                if (EPI == 2) {
                    if (RESF32) v += ((const float*)res)[(size_t)(row + r) * N + col];
                    else        v += bf2f(((const u16*)res)[(size_t)(row + r) * N + col]);
                }
                if (OUTF32) ((float*)Cv)[(size_t)(row + r) * N + col] = v;
                else        ((u16*)Cv)[(size_t)(row + r) * N + col] = f2b(v);
            }
        }
    }
}

// ---------------- 128x256 8-phase GEMM (Wpost, W2) ----------------
template <int EPI, bool OUTF32, bool RESF32>
__global__ __launch_bounds__(512, 2) void gemm8h_bt_k(const u16* __restrict__ A,
                                                      const u16* __restrict__ B,
                                                      const float* __restrict__ bias,
                                                      const void* __restrict__ res,
                                                      void* __restrict__ Cv,
                                                      int M, int N, int K) {
    __shared__ __align__(16) u16 lds[49152];   // 96 KiB
    int bx, by; xcd_swizzle(bx, by);
    const int m0 = by * 128, n0 = bx * 256;
    const int t = threadIdx.x, wave = t >> 6, lane = t & 63;
    const int quad = lane >> 4, ln = lane & 15;
    const int wm = (wave >> 2) * 64, wn = (wave & 3) * 64;

    floatx4 acc[4][4];
    #pragma unroll
    for (int mf = 0; mf < 4; mf++)
        #pragma unroll
        for (int nf = 0; nf < 4; nf++) acc[mf][nf] = (floatx4)0.0f;

    gemm8h_core(A, B, K, K >> 6, m0, n0, lds, acc);

    #pragma unroll
    for (int nf = 0; nf < 4; nf++) {
        int col = n0 + wn + nf * 16 + ln;
        float bv = bias[col];
        #pragma unroll
        for (int mf = 0; mf < 4; mf++) {
            int row = m0 + wm + mf * 16 + quad * 4;
            #pragma unroll
            for (int r = 0; r < 4; r++) {
                float v = acc[mf][nf][r] + bv;
                if (EPI == 1) v = fmaxf(v, 0.0f);
                if (EPI == 2) {
                    if (RESF32) v += ((const float*)res)[(size_t)(row + r) * N + col];
                    else        v += bf2f(((const u16*)res)[(size_t)(row + r) * N + col]);
                }
                if (OUTF32) ((float*)Cv)[(size_t)(row + r) * N + col] = v;
                else        ((u16*)Cv)[(size_t)(row + r) * N + col] = f2b(v);
            }
        }
    }
}

// ---------------- 128x256 fused QKV GEMM: q cols scaled by softplus(pds)*LOG2E --------
__global__ __launch_bounds__(512, 2) void gemm8h_qkv_k(const u16* __restrict__ A,
                                                       const u16* __restrict__ B,
                                                       const float* __restrict__ bq,
                                                       const float* __restrict__ bk,
                                                       const float* __restrict__ bv,
                                                       const float* __restrict__ pds,
                                                       u16* __restrict__ C) {
    const int K = 1024, N = 3072;
    __shared__ __align__(16) u16 lds[49152];
    int bx, by; xcd_swizzle(bx, by);
    const int m0 = by * 128, n0 = bx * 256;
    const int t = threadIdx.x, wave = t >> 6, lane = t & 63;
    const int quad = lane >> 4, ln = lane & 15;
    const int wm = (wave >> 2) * 64, wn = (wave & 3) * 64;

    floatx4 acc[4][4];
    #pragma unroll
    for (int mf = 0; mf < 4; mf++)
        #pragma unroll
        for (int nf = 0; nf < 4; nf++) acc[mf][nf] = (floatx4)0.0f;

    gemm8h_core(A, B, K, K >> 6, m0, n0, lds, acc);

    #pragma unroll
    for (int nf = 0; nf < 4; nf++) {
        int col = n0 + wn + nf * 16 + ln;
        float bv_, sc = 1.0f;
        if (col < 1024) {
            bv_ = bq[col];
            float xp = pds[col & 63];
            float sp = (xp > 20.0f) ? xp : log1pf(__expf(xp));
            sc = R_PDS * sp * LOG2E;            // fold log2(e): attn uses exp2
        } else if (col < 2048) bv_ = bk[col - 1024];
        else                   bv_ = bv[col - 2048];
        #pragma unroll
        for (int mf = 0; mf < 4; mf++) {
            int row = m0 + wm + mf * 16 + quad * 4;
            #pragma unroll
            for (int r = 0; r < 4; r++)
                C[(size_t)(row + r) * N + col] = f2b((acc[mf][nf][r] + bv_) * sc);
        }
    }
}

// ---------------- V transpose: qkv v-part -> vT[bh][d][s] ----------------
__global__ __launch_bounds__(256) void transpose_v_k(const u16* __restrict__ qkv, u16* __restrict__ vT) {
    __shared__ u16 tile[64][65];
    int st = blockIdx.x, bh = blockIdx.y;
    int b = bh >> 4, h = bh & 15;
    const u16* vb = qkv + (size_t)(b * 2048 + st * 64) * 3072 + 2048 + h * 64;
    int t = threadIdx.x;
    for (int i = t; i < 4096; i += 256) {
        int s = i >> 6, d = i & 63;
        tile[s][d] = vb[(size_t)s * 3072 + d];
    }
    __syncthreads();
    u16* ob = vT + (size_t)bh * 131072 + st * 64;
    for (int i = t; i < 4096; i += 256) {
        int d = i >> 6, s = i & 63;
        ob[(size_t)d * 2048 + s] = tile[s][d];
    }
}

// ---------------- flash attention: 1 block = (bh, 256 q rows), BKV=64 ------------------
// 4 waves x 64 q rows each (4 m-tiles): K/V fragment LDS traffic amortized 4x.
// All LDS XOR-swizzled (byte ^= (row&7)<<4, 128B row stride, same as GEMM cores) ->
// conflict-free b128 frag reads; everything is reg-staged so both sides swizzle (rule 21).
// XCD-chunked block remap: 8 q-tiles sharing one head's K/V land on one XCD (4MB ~ L2).
// S^T = mfma(K,Q): lane holds 4 consecutive kv of one q row -> b64 P stores. P rows are
// wave-local (wm..wm+63); no extra barriers. LDS 48 KB. P = exp2(S), log2e pre-folded.
__global__ __launch_bounds__(256, 2) void attn_k(const u16* __restrict__ qkv,
                                                 const u16* __restrict__ vT,
                                                 const float* __restrict__ mask,
                                                 const int* __restrict__ flag,
                                                 u16* __restrict__ o) {
    __shared__ __align__(16) u16 QPs[256 * 64];  // Q during setup, then P (rows wave-local)
    __shared__ __align__(16) u16 Ks[64 * 64];
    __shared__ __align__(16) u16 Vs[64 * 64];    // rows = d, cols = kv

    const int t = threadIdx.x, wave = t >> 6, lane = t & 63;
    const int quad = lane >> 4, ln = lane & 15;
    // lin = 9 bits [c:b:a]; qt = b, bh = a*8+c -> 8 qt-blocks of a head share XCD a.
    const int lin = blockIdx.y * 8 + blockIdx.x;
    const int qt = (lin >> 3) & 7;
    const int bh = ((lin & 7) << 3) | (lin >> 6);
    const int b = bh >> 4, h = bh & 15;
    const int q0 = qt * 256;
    const int wm = wave * 64;

    // stage Q tile (256 rows x 64 d; pre-scaled by softplus*log2e in QKV epilogue)
    const u16* qb = qkv + (size_t)(b * 2048 + q0) * 3072 + h * 64;
    #pragma unroll
    for (int i = 0; i < 8; i++) {
        int c = t + i * 256;
        int row = c >> 3, seg = c & 7;
        int byt = (seg * 16) ^ ((row & 7) << 4);
        *(uint4*)&QPs[row * 64 + (byt >> 1)] = *(const uint4*)(qb + (size_t)row * 3072 + seg * 8);
    }
    __syncthreads();

    // hoist Q fragments (rows wm..wm+63: wave-local; later P writes reuse same rows)
    short8 qf[4][2];
    #pragma unroll
    for (int mt = 0; mt < 4; mt++)
        #pragma unroll
        for (int ks = 0; ks < 2; ks++) {
            int row = wm + mt * 16 + ln;
            int byt = (ks * 64 + quad * 16) ^ ((ln & 7) << 4);
            qf[mt][ks] = *(const short8*)&QPs[row * 64 + (byt >> 1)];
        }

    short8 ones_f;
    #pragma unroll
    for (int i = 0; i < 8; i++) ones_f[i] = (short)0x3F80;   // bf16 1.0

    floatx4 acc_o[4][4], acc_l[4];
    #pragma unroll
    for (int mt = 0; mt < 4; mt++) {
        acc_l[mt] = (floatx4)0.0f;
        #pragma unroll
        for (int dt = 0; dt < 4; dt++) acc_o[mt][dt] = (floatx4)0.0f;
    }

    const int mflag = *flag;
    const u16* kb = qkv + (size_t)(b * 2048) * 3072 + 1024 + h * 64;
    const u16* vg = vT + (size_t)bh * 131072;

    // per-thread staging coordinates: rows r0 and r0+32, 16B segment sseg (swizzled dest)
    const int r0 = t >> 3, sseg = t & 7;
    const int wofs = (((sseg * 16) ^ ((r0 & 7) << 4)) >> 1);   // same for r0 and r0+32
    const int s0 = sseg * 8;
    const u16* kp0 = kb + (size_t)r0 * 3072 + s0;
    const u16* kp1 = kb + (size_t)(r0 + 32) * 3072 + s0;
    const u16* vp0 = vg + (size_t)r0 * 2048 + s0;
    const u16* vp1 = vg + (size_t)(r0 + 32) * 2048 + s0;

    // prefetch tile 0 into named registers
    uint4 kr0 = *(const uint4*)(kp0);
    uint4 kr1 = *(const uint4*)(kp1);
    uint4 vr0 = *(const uint4*)(vp0);
    uint4 vr1 = *(const uint4*)(vp1);

    for (int kv0 = 0; kv0 < 2048; kv0 += 64) {
        __syncthreads();                       // all waves done reading prev Ks/Vs
        *(uint4*)&Ks[r0 * 64 + wofs]        = kr0;
        *(uint4*)&Ks[(r0 + 32) * 64 + wofs] = kr1;
        *(uint4*)&Vs[r0 * 64 + wofs]        = vr0;
        *(uint4*)&Vs[(r0 + 32) * 64 + wofs] = vr1;
        __syncthreads();
        if (kv0 + 64 < 2048) {                 // uniform branch; loads overlap compute
            size_t ko = (size_t)(kv0 + 64) * 3072;
            int    vo = kv0 + 64;
            kr0 = *(const uint4*)(kp0 + ko);
            kr1 = *(const uint4*)(kp1 + ko);
            vr0 = *(const uint4*)(vp0 + vo);
            vr1 = *(const uint4*)(vp1 + vo);
        }

        // S^T = K Q^T per 16-kv block; lane: q col = wm+mt*16+ln, kv = nt*16+quad*4+r.
        #pragma unroll
        for (int nt = 0; nt < 4; nt++) {
            floatx4 sa[4];
            #pragma unroll
            for (int mt = 0; mt < 4; mt++) sa[mt] = (floatx4)0.0f;
            #pragma unroll
            for (int ks = 0; ks < 2; ks++) {
                int byt = (ks * 64 + quad * 16) ^ ((ln & 7) << 4);
                short8 kf = *(const short8*)&Ks[(nt * 16 + ln) * 64 + (byt >> 1)];
                #pragma unroll
                for (int mt = 0; mt < 4; mt++)
                    sa[mt] = __builtin_amdgcn_mfma_f32_16x16x32_bf16(kf, qf[mt][ks], sa[mt], 0, 0, 0);
            }
            if (mflag) {
                #pragma unroll
                for (int mt = 0; mt < 4; mt++)
                    #pragma unroll
                    for (int r = 0; r < 4; r++) {
                        int kc = kv0 + nt * 16 + quad * 4 + r;
                        sa[mt][r] += mask[(size_t)(q0 + wm + mt * 16 + ln) * 2048 + kc] * LOG2E;
                    }
            }
            // P = exp2(min(S,80)): 4 contiguous kv of one q row -> single b64 store
            #pragma unroll
            for (int mt = 0; mt < 4; mt++) {
                uint2 w;
                w.x = pk2(__builtin_amdgcn_exp2f(fminf(sa[mt][0], 80.0f)),
                          __builtin_amdgcn_exp2f(fminf(sa[mt][1], 80.0f)));
                w.y = pk2(__builtin_amdgcn_exp2f(fminf(sa[mt][2], 80.0f)),
                          __builtin_amdgcn_exp2f(fminf(sa[mt][3], 80.0f)));
                int row = wm + mt * 16 + ln;
                int byt = (nt * 32 + quad * 8) ^ ((ln & 7) << 4);
                *(uint2*)&QPs[row * 64 + (byt >> 1)] = w;
            }
        }

        // O += P V ; l += P·1  (V fragments shared across all 4 m-tiles)
        #pragma unroll
        for (int ks = 0; ks < 2; ks++) {
            short8 a[4];
            #pragma unroll
            for (int mt = 0; mt < 4; mt++) {
                int row = wm + mt * 16 + ln;
                int byt = (ks * 64 + quad * 16) ^ ((ln & 7) << 4);
                a[mt] = *(const short8*)&QPs[row * 64 + (byt >> 1)];
            }
            #pragma unroll
            for (int mt = 0; mt < 4; mt++)
                acc_l[mt] = __builtin_amdgcn_mfma_f32_16x16x32_bf16(a[mt], ones_f, acc_l[mt], 0, 0, 0);
            #pragma unroll
            for (int dt = 0; dt < 4; dt++) {
                int byt = (ks * 64 + quad * 16) ^ ((ln & 7) << 4);
                short8 bfr = *(const short8*)&Vs[(dt * 16 + ln) * 64 + (byt >> 1)];
                #pragma unroll
                for (int mt = 0; mt < 4; mt++)
                    acc_o[mt][dt] = __builtin_amdgcn_mfma_f32_16x16x32_bf16(a[mt], bfr, acc_o[mt][dt], 0, 0, 0);
            }
        }
    }

    // write O -> o[b, s, h, d] bf16 (row stride 1024)
    u16* ob = o + (size_t)(b * 2048 + q0) * 1024 + h * 64;
    #pragma unroll
    for (int mt = 0; mt < 4; mt++) {
        #pragma unroll
        for (int r = 0; r < 4; r++) {
            float inv = 1.0f / acc_l[mt][r];
            int row = wm + mt * 16 + quad * 4 + r;
            #pragma unroll
            for (int dt = 0; dt < 4; dt++)
                ob[(size_t)row * 1024 + dt * 16 + ln] = f2b(acc_o[mt][dt][r] * inv);
        }
    }
}

extern "C" void kernel_launch(void* const* d_in, const int* in_sizes, int n_in,
                              void* d_out, int out_size, void* d_ws, size_t ws_size,
                              hipStream_t stream) {
    const float* inp    = (const float*)d_in[0];
    const float* mask   = (const float*)d_in[1];
    const float* rms_s  = (const float*)d_in[2];
    const float* Wq     = (const float*)d_in[3];
    const float* bq     = (const float*)d_in[4];
    const float* Wk     = (const float*)d_in[5];
    const float* bk     = (const float*)d_in[6];
    const float* Wv     = (const float*)d_in[7];
    const float* bv     = (const float*)d_in[8];
    const float* pds    = (const float*)d_in[9];
    const float* Wpost  = (const float*)d_in[10];
    const float* bpost  = (const float*)d_in[11];
    const float* ln_s   = (const float*)d_in[12];
    const float* ln_b   = (const float*)d_in[13];
    const float* W1     = (const float*)d_in[14];
    const float* b1     = (const float*)d_in[15];
    const float* W2     = (const float*)d_in[16];
    const float* b2     = (const float*)d_in[17];
    float* out = (float*)d_out;

    char* w = (char*)d_ws;
    const size_t MB = 1u << 20;
    u16* W1b   = (u16*)(w + 0 * MB);      // [0,8)
    u16* W2b   = (u16*)(w + 8 * MB);      // [8,16)
    u16* qkv   = (u16*)(w + 16 * MB);     // [16,64) -> f1 [16,80)
    u16* x     = (u16*)(w + 64 * MB);     // [64,80) -> o
    u16* o     = (u16*)(w + 64 * MB);
    u16* Wqkvb = (u16*)(w + 80 * MB);     // [80,86)
    u16* Wpb   = (u16*)(w + 86 * MB);     // [86,88)
    u16* yln   = (u16*)(w + 80 * MB);     // [80,96) after Wq..p dead
    u16* vT    = (u16*)(w + 96 * MB);     // [96,112) -> hb
    u16* hb    = (u16*)(w + 96 * MB);
    u16* f1    = (u16*)(w + 16 * MB);
    int* flag  = (int*)(w + 112 * MB);

    f2b_all_k<<<12288, 256, 0, stream>>>(Wq, Wk, Wv, Wpost, W1, W2, Wqkvb, Wpb, W1b, W2b, flag);
    mask_any_k<<<4096, 256, 0, stream>>>(mask, flag);

    rmsnorm_k<<<8192, 256, 0, stream>>>(inp, rms_s, x);

    gemm8h_qkv_k<<<dim3(12, 64), 512, 0, stream>>>(x, Wqkvb, bq, bk, bv, pds, qkv);

    transpose_v_k<<<dim3(32, 64), 256, 0, stream>>>(qkv, vT);

    attn_k<<<dim3(8, 64), 256, 0, stream>>>(qkv, vT, mask, flag, o);

    gemm8h_bt_k<2, false, true><<<dim3(4, 64), 512, 0, stream>>>(o, Wpb, bpost, inp, hb, 8192, 1024, 1024);

    layernorm_k<<<8192, 256, 0, stream>>>(hb, ln_s, ln_b, yln);

    gemm8_bt_k<1, false, true><<<dim3(16, 32), 512, 0, stream>>>(yln, W1b, b1, nullptr, f1, 8192, 4096, 1024);
    gemm8h_bt_k<2, true, false><<<dim3(4, 64), 512, 0, stream>>>(f1, W2b, b2, hb, out, 8192, 1024, 4096);
}